// Round 7
// baseline (316.805 us; speedup 1.0000x reference)
//
#include <hip/hip_runtime.h>

#define HW 512
#define NPIX (HW * HW)        // 262144 pixels; u8 table = 256 KB, L2-resident per XCD
#define THREADS 256           // 4 waves/block
#define BLOCKS 2048           // 2048*256 = 524288 threads; 8 blocks/CU
#define NB 2                  // elems per round
#define RNDS 8                // 2*8 = 16 elems/thread; 524288*16 = 8388608 = N

// Reference constants
#define EPS_F  1e-10f
constexpr double B_d  = 1.0 + 0.1 + 0.05;        // 1.15
constexpr double BR_d = 1.0 + 0.1 - 0.05;        // 1.05
#define B_F    ((float)B_d)
#define INVB_F ((float)(1.0 / B_d))
#define BR_F   ((float)BR_d)
#define BL_F   ((float)(1.0 / BR_d))

typedef __attribute__((ext_vector_type(4))) int ivec4;

// u8 table: k = round(m*255), v = (k+1)/256. |dv| <= 1/512; measured final
// absmax 1.95e-3 vs threshold 7.07e-3.
__global__ void build_v(const float* __restrict__ vin,
                        unsigned char* __restrict__ vq,
                        float* __restrict__ out) {
    int i = blockIdx.x * blockDim.x + threadIdx.x;
    if (i == 0) *out = 0.0f;                     // fold d_out zero-init here
    if (i < NPIX) {
        float s = vin[i] + vin[i + NPIX] + vin[i + 2 * NPIX];
        float m = s * (1.0f / 3.0f);
        vq[i] = (unsigned char)__float2int_rn(m * 255.0f);
    }
}

__device__ __forceinline__ float rcp_fast(float x) {
#if __has_builtin(__builtin_amdgcn_rcpf)
    return __builtin_amdgcn_rcpf(x);             // v_rcp_f32, ~1 ulp — margin is 3.6x
#else
    return 1.0f / x;
#endif
}

__device__ __forceinline__ float per_loss(float r1, float r2, int d) {
    float ratio = r1 * rcp_fast(r2 + EPS_F);
    float rinv  = r2 * rcp_fast(r1 + EPS_F);
    float l1 = (ratio > INVB_F) ? (ratio - INVB_F + (B_F - rinv)) : 0.0f;
    float l2 = (ratio < B_F)    ? (B_F - ratio + (rinv - INVB_F)) : 0.0f;
    float l0 = (ratio > BR_F)   ? (ratio - BR_F + (BL_F - rinv))
             : ((ratio < BL_F)  ? (BL_F - ratio + (rinv - BR_F)) : 0.0f);
    return (d == 1) ? l1 : ((d == 2) ? l2 : l0);
}

// ---- pipeline building blocks (sched_barrier(0) at call sites keeps the
// issue order: the compiler may not sink loads down to their consumers) ----

__device__ __forceinline__ void load_c(ivec4 (&cc)[NB], const ivec4* __restrict__ coords,
                                       int tid, int T, int ofs) {
    #pragma unroll
    for (int k = 0; k < NB; ++k)
        cc[k] = __builtin_nontemporal_load(&coords[tid + (ofs + k) * T]);
}

__device__ __forceinline__ void load_dw(int (&dd)[NB], float (&ww)[NB],
                                        const int* __restrict__ darker,
                                        const float* __restrict__ weights,
                                        int tid, int T, int ofs) {
    #pragma unroll
    for (int k = 0; k < NB; ++k)
        dd[k] = __builtin_nontemporal_load(&darker[tid + (ofs + k) * T]);
    #pragma unroll
    for (int k = 0; k < NB; ++k)
        ww[k] = __builtin_nontemporal_load(&weights[tid + (ofs + k) * T]);
}

// All-global byte gathers (table is L2-resident; streams are NT so they
// don't evict it).
__device__ __forceinline__ void gather_issue(const ivec4 (&cc)[NB],
        unsigned (&q1)[NB], unsigned (&q2)[NB],
        const unsigned char* __restrict__ vq) {
    #pragma unroll
    for (int k = 0; k < NB; ++k) {
        q1[k] = vq[cc[k].y * HW + cc[k].x];
        q2[k] = vq[cc[k].w * HW + cc[k].z];
    }
}

__device__ __forceinline__ void consume(const unsigned (&q1)[NB], const unsigned (&q2)[NB],
                                        const int (&dd)[NB], const float (&ww)[NB],
                                        float& acc) {
    #pragma unroll
    for (int k = 0; k < NB; ++k) {
        float r1 = (float)(q1[k] + 1) * (1.0f / 256.0f);
        float r2 = (float)(q2[k] + 1) * (1.0f / 256.0f);
        acc += ww[k] * per_loss(r1, r2, dd[k]);
    }
}

#define SBAR() __builtin_amdgcn_sched_barrier(0)

// The clean high-occupancy experiment R4 failed to run (it spilled at a
// 32-VGPR budget: WRITE_SIZE 51 MB scratch). amdgpu_waves_per_eu(8,8) PINS
// the allocator at 8 waves/EU -> 64-VGPR budget (R5 proved pinning works
// where launch_bounds' minimum was ignored). NB=2 state ~55 regs -> fits.
// No LDS table: it only saved ~6 us of gather traffic but cost half the
// wave slots (4 waves/SIMD), which every counter snapshot says is the
// actual starvation (VALUBusy ~5%, HBM ~15%, nothing busy).
__global__ __launch_bounds__(THREADS)
__attribute__((amdgpu_waves_per_eu(8, 8)))
void whdr_kernel(
        const unsigned char* __restrict__ vq,
        const ivec4* __restrict__ coords,
        const int*   __restrict__ darker,
        const float* __restrict__ weights,
        float*       __restrict__ out,
        int n) {
    const int tid = blockIdx.x * THREADS + threadIdx.x;
    const int T   = BLOCKS * THREADS;            // 524288
    float acc = 0.0f;

    if (n == T * NB * RNDS) {
        // ---- steady-state: 8 rounds; streams A/B ping-pong 2 rounds ahead,
        // gathers double-buffered 1 round ahead ----
        ivec4 cA[NB], cB[NB];
        int   dA[NB], dB[NB];
        float wA[NB], wB[NB];
        unsigned qA1[NB], qA2[NB], qB1[NB], qB2[NB];

        load_c (cA, coords, tid, T, 0);
        load_dw(dA, wA, darker, weights, tid, T, 0);
        load_c (cB, coords, tid, T, NB);
        load_dw(dB, wB, darker, weights, tid, T, NB);
        gather_issue(cA, qA1, qA2, vq);                SBAR();  // G0

        // RPF(r): gather for round r+1, prefetch streams for round r+2,
        // consume round r. CUR alternates A,B.
#define RPF(r, CUR, NXT) \
        gather_issue(c##NXT, q##NXT##1, q##NXT##2, vq);            SBAR(); \
        load_c (c##CUR, coords, tid, T, (r + 2) * NB);             SBAR(); \
        consume(q##CUR##1, q##CUR##2, d##CUR, w##CUR, acc); \
        load_dw(d##CUR, w##CUR, darker, weights, tid, T, (r + 2) * NB); SBAR();

        RPF(0, A, B)  // consume r0(A), gather r1(B), prefetch r2 -> A
        RPF(1, B, A)
        RPF(2, A, B)
        RPF(3, B, A)
        RPF(4, A, B)
        RPF(5, B, A)
#undef RPF
        // round 6: gather r7(B), consume r6(A) — no more stream prefetch
        gather_issue(cB, qB1, qB2, vq);                SBAR();
        consume(qA1, qA2, dA, wA, acc);
        // round 7: drain
        consume(qB1, qB2, dB, wB, acc);
    } else {
        // ---- generic fallback (any n) ----
        const int TT = gridDim.x * THREADS;
        for (int i = tid; i < n; i += TT) {
            ivec4 c = coords[i];
            unsigned a = vq[c.y * HW + c.x];
            unsigned b = vq[c.w * HW + c.z];
            float r1 = (float)(a + 1) * (1.0f / 256.0f);
            float r2 = (float)(b + 1) * (1.0f / 256.0f);
            acc += weights[i] * per_loss(r1, r2, darker[i]);
        }
    }

    // wave-64 shuffle reduction, then tiny LDS block reduction (4 waves)
    #pragma unroll
    for (int off = 32; off > 0; off >>= 1)
        acc += __shfl_down(acc, off, 64);
    __shared__ float wsum[THREADS / 64];
    int lane = threadIdx.x & 63;
    int wid  = threadIdx.x >> 6;
    if (lane == 0) wsum[wid] = acc;
    __syncthreads();
    if (threadIdx.x == 0) {
        float s = 0.0f;
        #pragma unroll
        for (int i = 0; i < THREADS / 64; ++i) s += wsum[i];
        atomicAdd(out, s / (float)n);            // n = 2^23 -> exact
    }
}

extern "C" void kernel_launch(void* const* d_in, const int* in_sizes, int n_in,
                              void* d_out, int out_size, void* d_ws, size_t ws_size,
                              hipStream_t stream) {
    const float* v_input = (const float*)d_in[0];  // (3,512,512) f32
    const ivec4* coords  = (const ivec4*)d_in[1];  // (N,4) i32
    const int*   darker  = (const int*)d_in[2];    // (N,) i32
    const float* weights = (const float*)d_in[3];  // (N,) f32
    float* out = (float*)d_out;
    unsigned char* vq = (unsigned char*)d_ws;      // 256 KB u8 v table
    int n = in_sizes[2];                           // N

    build_v<<<(NPIX + 255) / 256, 256, 0, stream>>>(v_input, vq, out);
    whdr_kernel<<<BLOCKS, THREADS, 0, stream>>>(vq, coords, darker, weights, out, n);
}

// Round 8
// 263.380 us; speedup vs baseline: 1.2028x; 1.2028x over previous
//
#include <hip/hip_runtime.h>

#define HW 512
#define NPIX (HW * HW)        // 262144 pixels; u8 table = 256 KB
#define LDS_PIX 81920         // 80 KB slice -> 2 blocks/CU (2x80=160KB), f=31.25%
#define THREADS 1024          // 16 waves/block
#define BLOCKS 512            // 2 blocks/CU co-resident; 524288 threads
#define NB 2                  // elems per round (live state ~55 regs < 64 budget)
#define RNDS 8                // 2*8 = 16 elems/thread; 524288*16 = 8388608 = N

// Reference constants
#define EPS_F  1e-10f
constexpr double B_d  = 1.0 + 0.1 + 0.05;        // 1.15
constexpr double BR_d = 1.0 + 0.1 - 0.05;        // 1.05
#define B_F    ((float)B_d)
#define INVB_F ((float)(1.0 / B_d))
#define BR_F   ((float)BR_d)
#define BL_F   ((float)(1.0 / BR_d))

typedef __attribute__((ext_vector_type(4))) int ivec4;

// u8 table: k = round(m*255), v = (k+1)/256. |dv| <= 1/512; measured final
// absmax 1.95e-3 vs threshold 7.07e-3.
__global__ void build_v(const float* __restrict__ vin,
                        unsigned char* __restrict__ vq,
                        float* __restrict__ out) {
    int i = blockIdx.x * blockDim.x + threadIdx.x;
    if (i == 0) *out = 0.0f;                     // fold d_out zero-init here
    if (i < NPIX) {
        float s = vin[i] + vin[i + NPIX] + vin[i + 2 * NPIX];
        float m = s * (1.0f / 3.0f);
        vq[i] = (unsigned char)__float2int_rn(m * 255.0f);
    }
}

__device__ __forceinline__ float rcp_fast(float x) {
#if __has_builtin(__builtin_amdgcn_rcpf)
    return __builtin_amdgcn_rcpf(x);             // v_rcp_f32, ~1 ulp — margin is 3.6x
#else
    return 1.0f / x;
#endif
}

__device__ __forceinline__ float per_loss(float r1, float r2, int d) {
    float ratio = r1 * rcp_fast(r2 + EPS_F);
    float rinv  = r2 * rcp_fast(r1 + EPS_F);
    float l1 = (ratio > INVB_F) ? (ratio - INVB_F + (B_F - rinv)) : 0.0f;
    float l2 = (ratio < B_F)    ? (B_F - ratio + (rinv - INVB_F)) : 0.0f;
    float l0 = (ratio > BR_F)   ? (ratio - BR_F + (BL_F - rinv))
             : ((ratio < BL_F)  ? (BL_F - ratio + (rinv - BR_F)) : 0.0f);
    return (d == 1) ? l1 : ((d == 2) ? l2 : l0);
}

// ---- pipeline building blocks (sched_barrier(0) at call sites keeps the
// issue order: the compiler may not sink loads down to their consumers) ----

__device__ __forceinline__ void load_c(ivec4 (&cc)[NB], const ivec4* __restrict__ coords,
                                       int tid, int T, int ofs) {
    #pragma unroll
    for (int k = 0; k < NB; ++k)
        cc[k] = __builtin_nontemporal_load(&coords[tid + (ofs + k) * T]);
}

__device__ __forceinline__ void load_dw(int (&dd)[NB], float (&ww)[NB],
                                        const int* __restrict__ darker,
                                        const float* __restrict__ weights,
                                        int tid, int T, int ofs) {
    #pragma unroll
    for (int k = 0; k < NB; ++k)
        dd[k] = __builtin_nontemporal_load(&darker[tid + (ofs + k) * T]);
    #pragma unroll
    for (int k = 0; k < NB; ++k)
        ww[k] = __builtin_nontemporal_load(&weights[tid + (ofs + k) * T]);
}

// Hybrid gather: 31% of lanes hit LDS (off the TA), rest go global (table is
// L2-resident; NT streams don't evict it). Keep if/else form: masked
// ds_read_u8 + global_load_ubyte.
__device__ __forceinline__ void gather_issue(const ivec4 (&cc)[NB],
        unsigned (&q1)[NB], unsigned (&q2)[NB],
        const unsigned char* lv, const unsigned char* __restrict__ vq) {
    #pragma unroll
    for (int k = 0; k < NB; ++k) {
        int i1 = cc[k].y * HW + cc[k].x;
        int i2 = cc[k].w * HW + cc[k].z;
        if (i1 < LDS_PIX) q1[k] = lv[i1]; else q1[k] = vq[i1];
        if (i2 < LDS_PIX) q2[k] = lv[i2]; else q2[k] = vq[i2];
    }
}

__device__ __forceinline__ void consume(const unsigned (&q1)[NB], const unsigned (&q2)[NB],
                                        const int (&dd)[NB], const float (&ww)[NB],
                                        float& acc) {
    #pragma unroll
    for (int k = 0; k < NB; ++k) {
        float r1 = (float)(q1[k] + 1) * (1.0f / 256.0f);
        float r2 = (float)(q2[k] + 1) * (1.0f / 256.0f);
        acc += ww[k] * per_loss(r1, r2, dd[k]);
    }
}

#define SBAR() __builtin_amdgcn_sched_barrier(0)

// Allocator evidence: 1024-thread blocks naturally get a 64-VGPR budget (R2);
// 256-thread blocks get 32 and SPILL regardless of waves_per_eu pins (R4/R7:
// WRITE_SIZE 45-51 MB scratch, 135 us). So: 1024-thread blocks + NB=2 state
// (~55 live regs < 64) + 80 KB LDS -> 2 blocks/CU = 8 waves/SIMD, no spill.
__global__ __launch_bounds__(THREADS)
void whdr_kernel(
        const unsigned char* __restrict__ vq,
        const ivec4* __restrict__ coords,
        const int*   __restrict__ darker,
        const float* __restrict__ weights,
        float*       __restrict__ out,
        int n) {
    __shared__ unsigned char lv[LDS_PIX];        // 80 KB
    const int tid = blockIdx.x * THREADS + threadIdx.x;
    const int T   = BLOCKS * THREADS;            // 524288
    float acc = 0.0f;

    if (n == T * NB * RNDS) {
        // ---- steady-state: 8 rounds; streams A/B ping-pong 2 rounds ahead,
        // gathers double-buffered 1 round ahead ----
        ivec4 cA[NB], cB[NB];
        int   dA[NB], dB[NB];
        float wA[NB], wB[NB];
        unsigned qA1[NB], qA2[NB], qB1[NB], qB2[NB];

        load_c (cA, coords, tid, T, 0);
        load_dw(dA, wA, darker, weights, tid, T, 0);
        load_c (cB, coords, tid, T, NB);
        load_dw(dB, wB, darker, weights, tid, T, NB);
        {   // cooperative LDS fill: 81920 B / 1024 thr = 80 B/thr, 16B coalesced
            const uint4* s4 = (const uint4*)vq;
            uint4* d4 = (uint4*)lv;
            #pragma unroll
            for (int j = threadIdx.x; j < LDS_PIX / 16; j += THREADS) d4[j] = s4[j];
        }
        __syncthreads();
        gather_issue(cA, qA1, qA2, lv, vq);            SBAR();  // G0

        // RPF(r): gather for round r+1, prefetch streams for round r+2,
        // consume round r. CUR alternates A,B.
#define RPF(r, CUR, NXT) \
        gather_issue(c##NXT, q##NXT##1, q##NXT##2, lv, vq);        SBAR(); \
        load_c (c##CUR, coords, tid, T, (r + 2) * NB);             SBAR(); \
        consume(q##CUR##1, q##CUR##2, d##CUR, w##CUR, acc); \
        load_dw(d##CUR, w##CUR, darker, weights, tid, T, (r + 2) * NB); SBAR();

        RPF(0, A, B)
        RPF(1, B, A)
        RPF(2, A, B)
        RPF(3, B, A)
        RPF(4, A, B)
        RPF(5, B, A)
#undef RPF
        // round 6: gather r7(B), consume r6(A) — no more stream prefetch
        gather_issue(cB, qB1, qB2, lv, vq);            SBAR();
        consume(qA1, qA2, dA, wA, acc);
        // round 7: drain
        consume(qB1, qB2, dB, wB, acc);
    } else {
        // ---- generic fallback (any n) ----
        {
            const uint4* s4 = (const uint4*)vq;
            uint4* d4 = (uint4*)lv;
            for (int j = threadIdx.x; j < LDS_PIX / 16; j += THREADS) d4[j] = s4[j];
        }
        __syncthreads();
        const int TT = gridDim.x * THREADS;
        for (int i = tid; i < n; i += TT) {
            ivec4 c = coords[i];
            int i1 = c.y * HW + c.x, i2 = c.w * HW + c.z;
            unsigned a = (i1 < LDS_PIX) ? (unsigned)lv[i1] : (unsigned)vq[i1];
            unsigned b = (i2 < LDS_PIX) ? (unsigned)lv[i2] : (unsigned)vq[i2];
            float r1 = (float)(a + 1) * (1.0f / 256.0f);
            float r2 = (float)(b + 1) * (1.0f / 256.0f);
            acc += weights[i] * per_loss(r1, r2, darker[i]);
        }
    }

    // wave-64 shuffle reduction
    #pragma unroll
    for (int off = 32; off > 0; off >>= 1)
        acc += __shfl_down(acc, off, 64);
    // Reuse lv's LDS for the block reduction (table reads done; barrier
    // orders the reuse).
    __syncthreads();
    float* wsum = (float*)lv;
    int lane = threadIdx.x & 63;
    int wid  = threadIdx.x >> 6;                 // 16 waves
    if (lane == 0) wsum[wid] = acc;
    __syncthreads();
    if (threadIdx.x == 0) {
        float s = 0.0f;
        #pragma unroll
        for (int i = 0; i < THREADS / 64; ++i) s += wsum[i];
        atomicAdd(out, s / (float)n);            // n = 2^23 -> exact
    }
}

extern "C" void kernel_launch(void* const* d_in, const int* in_sizes, int n_in,
                              void* d_out, int out_size, void* d_ws, size_t ws_size,
                              hipStream_t stream) {
    const float* v_input = (const float*)d_in[0];  // (3,512,512) f32
    const ivec4* coords  = (const ivec4*)d_in[1];  // (N,4) i32
    const int*   darker  = (const int*)d_in[2];    // (N,) i32
    const float* weights = (const float*)d_in[3];  // (N,) f32
    float* out = (float*)d_out;
    unsigned char* vq = (unsigned char*)d_ws;      // 256 KB u8 v table
    int n = in_sizes[2];                           // N

    build_v<<<(NPIX + 255) / 256, 256, 0, stream>>>(v_input, vq, out);
    whdr_kernel<<<BLOCKS, THREADS, 0, stream>>>(vq, coords, darker, weights, out, n);
}